// Round 2
// baseline (560.332 us; speedup 1.0000x reference)
//
#include <hip/hip_runtime.h>

typedef unsigned short ushort_t;
typedef unsigned int   uint_t;
typedef __attribute__((ext_vector_type(8))) short  short8;
typedef __attribute__((ext_vector_type(4))) float  floatx4;

#define NROWS 131072
#define BM    64      // rows per block (one tower per block)
#define SX    328     // x-hat bf16 LDS row stride (ushorts); cols >=292 zeroed to 320
#define SH    264     // h bf16 LDS row stride (ushorts)

// d_ws bf16 region (ushort element offsets) — chunk-major: [kc][col(256)][k(32)]
#define W1_OFF 0        // 10 chunks
#define P1_OFF 81920    // 10 chunks
#define W2_OFF 163840   // 8 chunks
#define P2_OFF 229376   // 8 chunks
#define P3BF_OFF 294912 // 8 chunks x [16 cols][32] bf16 frag layout (cols>=10 zero)
#define BF16_BYTES 598016
// d_ws float region (float element offsets, base = ws + BF16_BYTES)
#define B1_OFF  0
#define PB1_OFF 256
#define B2_OFF  512
#define PB2_OFF 768
#define W3_OFF  1024
#define B3_OFF  3840
#define PB3_OFF 3841

__device__ __forceinline__ float b2f(ushort_t u){
    union { uint_t i; float f; } v; v.i = ((uint_t)u) << 16; return v.f;
}
__device__ __forceinline__ ushort_t f2b(float f){
    union { uint_t i; float f; } v; v.f = f;
    uint_t b = v.i;
    b += 0x7FFFu + ((b >> 16) & 1u);   // RNE
    return (ushort_t)(b >> 16);
}

// ---------------- prologue: fold LN gain/bias into linears, fp32 -> bf16 ----
__global__ __launch_bounds__(256) void bcq_prep(
    const float* __restrict__ ln1w, const float* __restrict__ ln1b,
    const float* __restrict__ ln2w, const float* __restrict__ ln2b,
    const float* __restrict__ ln3w, const float* __restrict__ ln3b,
    const float* __restrict__ n1g,  const float* __restrict__ n1b,
    const float* __restrict__ n2g,  const float* __restrict__ n2b,
    const float* __restrict__ n3g,  const float* __restrict__ n3b,
    const float* __restrict__ p1w,  const float* __restrict__ p1b,
    const float* __restrict__ p2w,  const float* __restrict__ p2b,
    const float* __restrict__ p3w,  const float* __restrict__ p3b,
    const float* __restrict__ pn1g, const float* __restrict__ pn1b,
    const float* __restrict__ pn2g, const float* __restrict__ pn2b,
    const float* __restrict__ pn3g, const float* __restrict__ pn3b,
    ushort_t* __restrict__ wbf, float* __restrict__ wf)
{
    const int bid = blockIdx.x, tid = threadIdx.x;
    if (bid < 128){
        // layer 1 (K=292 padded to 320): W1 then P1
        for (int i = bid*256 + tid; i < 163840; i += 128*256){
            const int which = i / 81920;            // 0=W1, 1=P1
            const int r  = i - which*81920;
            const int kc = r >> 13;                  // /8192
            const int t  = r & 8191;
            const int c  = t >> 5, kk = t & 31;
            const int k  = kc*32 + kk;
            const float* src = which ? p1w  : ln1w;
            const float* g   = which ? pn1g : n1g;
            ushort_t v = 0;
            if (k < 292) v = f2b(src[c*292 + k] * g[k]);
            wbf[i] = v;
        }
        // layer 2 (K=256): W2 then P2
        for (int i = bid*256 + tid; i < 131072; i += 128*256){
            const int which = i >> 16;
            const int r  = i & 65535;
            const int kc = r >> 13;
            const int t  = r & 8191;
            const int c  = t >> 5, kk = t & 31;
            const int k  = kc*32 + kk;
            const float* src = which ? p2w  : ln2w;
            const float* g   = which ? pn2g : n2g;
            wbf[W2_OFF + i] = f2b(src[c*256 + k] * g[k]);
        }
    } else if (bid < 384){
        const int d = (bid - 128)*4 + (tid >> 6);
        const int lane = tid & 63;
        const float *w, *nb, *bs; int K, outoff; const int c = d & 255;
        if (d < 256)      { w = ln1w; nb = n1b;  bs = ln1b; K = 292; outoff = B1_OFF; }
        else if (d < 512) { w = p1w;  nb = pn1b; bs = p1b;  K = 292; outoff = PB1_OFF; }
        else if (d < 768) { w = ln2w; nb = n2b;  bs = ln2b; K = 256; outoff = B2_OFF; }
        else              { w = p2w;  nb = pn2b; bs = p2b;  K = 256; outoff = PB2_OFF; }
        float s = 0.f;
        for (int k = lane; k < K; k += 64) s += w[c*K + k] * nb[k];
        for (int off = 32; off; off >>= 1) s += __shfl_down(s, off);
        if (lane == 0) wf[outoff + c] = s + bs[c];
    } else if (bid == 384){
        wf[W3_OFF + tid] = ln3w[tid] * n3g[tid];
        // P3 in bf16 MFMA B-frag layout: [kc][col(16)][kk(32)], cols >=10 zero
        for (int i = tid; i < 4096; i += 256){
            const int kc = i >> 9, t = i & 511, c = t >> 5, kk = t & 31;
            const int k = kc*32 + kk;
            ushort_t vv = 0;
            if (c < 10) vv = f2b(p3w[c*256 + k] * pn3g[k]);
            wbf[P3BF_OFF + i] = vv;
        }
    } else {
        const int g32 = tid >> 5, l32 = tid & 31;
        const int d = (bid - 385)*8 + g32;                   // valid < 11
        if (d < 11){
            const float* w  = (d == 0) ? ln3w : (p3w + (d-1)*256);
            const float* nb = (d == 0) ? n3b  : pn3b;
            float s = 0.f;
            for (int k = l32; k < 256; k += 32) s += w[k] * nb[k];
            for (int off = 16; off; off >>= 1) s += __shfl_xor(s, off);
            if (l32 == 0){
                if (d == 0) wf[B3_OFF] = s + ln3b[0];
                else        wf[PB3_OFF + d - 1] = s + p3b[d - 1];
            }
        }
    }
}

// ---------------- main ------------------------------------------------------
// GEMM: y[64x256] = relu(sIn @ W'^T + b'); fused LN epilogue writes normalized
// bf16 to sOut. 8 waves: wave w owns cols [w*32, w*32+32) over all 64 rows.
// Per kc: 4 A-frags (LDS), 2 B-frags (L2, depth-2 reg prefetch), 8 MFMAs.
// Safe for sOut aliasing sIn: all sIn reads complete before internal barrier 1.
template<int FULLKC>
__device__ __forceinline__ void gemm64ln(
    const ushort_t* sIn, int astride, const ushort_t* __restrict__ Wg,
    const float* __restrict__ biasf, ushort_t* sOut,
    float* sRed, float* sM, float* sR, int tid)
{
    const int lane = tid & 63, wave = tid >> 6;        // 8 waves
    const int l15 = lane & 15, quad = lane >> 4;
    const int colbase = wave * 32;
    const ushort_t* arow = sIn + l15*astride + quad*8; // + rt*16*astride + kc*32
    // chunk-major: frag addr = (colbase + nt*16 + l15)*32 + quad*8 + kc*8192
    const ushort_t* wl = Wg + (colbase + l15)*32 + quad*8;

    floatx4 acc[2][4];                                 // [nt][rt]
#pragma unroll
    for (int nt = 0; nt < 2; ++nt)
#pragma unroll
        for (int rt = 0; rt < 4; ++rt) acc[nt][rt] = (floatx4){0,0,0,0};

    short8 bb0[2], bb1[2];
#pragma unroll
    for (int nt = 0; nt < 2; ++nt) bb0[nt] = *(const short8*)(wl + nt*512);
#pragma unroll
    for (int nt = 0; nt < 2; ++nt) bb1[nt] = *(const short8*)(wl + nt*512 + 8192);

#pragma unroll
    for (int kc = 0; kc < FULLKC; ++kc){
        short8 bnew[2];
        if (kc + 2 < FULLKC){
#pragma unroll
            for (int nt = 0; nt < 2; ++nt)
                bnew[nt] = *(const short8*)(wl + nt*512 + (kc + 2)*8192);
        }
        short8 a[4];
#pragma unroll
        for (int rt = 0; rt < 4; ++rt)
            a[rt] = *(const short8*)(arow + rt*16*astride + kc*32);
#pragma unroll
        for (int nt = 0; nt < 2; ++nt){
            const short8 bc = (kc & 1) ? bb1[nt] : bb0[nt];
#pragma unroll
            for (int rt = 0; rt < 4; ++rt)
                acc[nt][rt] = __builtin_amdgcn_mfma_f32_16x16x32_bf16(a[rt], bc, acc[nt][rt], 0, 0, 0);
        }
        if (kc + 2 < FULLKC){
#pragma unroll
            for (int nt = 0; nt < 2; ++nt){
                if (kc & 1) bb1[nt] = bnew[nt]; else bb0[nt] = bnew[nt];
            }
        }
    }

    // ---- fused LN epilogue ----
    float bia[2];
#pragma unroll
    for (int nt = 0; nt < 2; ++nt) bia[nt] = biasf[colbase + nt*16 + l15];

    // y = relu(acc+bias) stored back into acc; per-(rt,i) row partials over 2 col-tiles
    float ps[4][4], pq[4][4];
#pragma unroll
    for (int rt = 0; rt < 4; ++rt)
#pragma unroll
        for (int i = 0; i < 4; ++i){
            float s = 0.f, q = 0.f;
#pragma unroll
            for (int nt = 0; nt < 2; ++nt){
                float y = fmaxf(acc[nt][rt][i] + bia[nt], 0.f);
                acc[nt][rt][i] = y;
                s += y; q += y*y;
            }
            ps[rt][i] = s; pq[rt][i] = q;
        }
    // reduce across the 16 lanes (cols) of the quad group
#pragma unroll
    for (int off = 1; off <= 8; off <<= 1){
#pragma unroll
        for (int rt = 0; rt < 4; ++rt)
#pragma unroll
            for (int i = 0; i < 4; ++i){
                ps[rt][i] += __shfl_xor(ps[rt][i], off);
                pq[rt][i] += __shfl_xor(pq[rt][i], off);
            }
    }
    if (l15 == 0){
#pragma unroll
        for (int rt = 0; rt < 4; ++rt)
#pragma unroll
            for (int i = 0; i < 4; ++i){
                const int row = rt*16 + quad*4 + i;
                sRed[row*16 + wave*2 + 0] = ps[rt][i];
                sRed[row*16 + wave*2 + 1] = pq[rt][i];
            }
    }
    __syncthreads();
    if (tid < 64){
        float ss = 0.f, qq = 0.f;
#pragma unroll
        for (int w = 0; w < 8; ++w){ ss += sRed[tid*16 + w*2]; qq += sRed[tid*16 + w*2 + 1]; }
        float m = ss * (1.f/256.f);
        float var = fmaxf(qq * (1.f/256.f) - m*m, 0.f);
        sM[tid] = m; sR[tid] = rsqrtf(var + 1e-5f);
    }
    __syncthreads();
    // normalize from registers, write bf16 (sOut may alias sIn — reads done)
#pragma unroll
    for (int rt = 0; rt < 4; ++rt)
#pragma unroll
        for (int i = 0; i < 4; ++i){
            const int row = rt*16 + quad*4 + i;
            const float m = sM[row], r = sR[row];
#pragma unroll
            for (int nt = 0; nt < 2; ++nt)
                sOut[row*SH + colbase + nt*16 + l15] = f2b((acc[nt][rt][i] - m) * r);
        }
}

__global__ __launch_bounds__(512)
__attribute__((amdgpu_waves_per_eu(6, 8)))   // 85-VGPR budget -> 3 blocks/CU with 46.6KB LDS
void bcq_main(
    const float* __restrict__ cum, const float* __restrict__ inp, const float* __restrict__ pos,
    const ushort_t* __restrict__ wbf, const float* __restrict__ wf, float* __restrict__ out)
{
    __shared__ __align__(16) char sMem[46592];
    ushort_t* sX     = (ushort_t*)sMem;            // 41984 B: x-hat (stride SX, 64 rows)
    ushort_t* sH     = (ushort_t*)sMem;            // alias:   h     (stride SH, 33792 B)
    float*    sRed   = (float*)(sMem + 41984);     // 4096 B scratch (score buf aliases)
    float*    sScore = sRed;                       // 2560 B used at the end
    float*    sM     = (float*)(sMem + 46080);     // 256 B
    float*    sR     = (float*)(sMem + 46336);     // 256 B

    const int tid = threadIdx.x;
    const int r8 = tid >> 3, p8 = tid & 7;         // 8 threads per row, 64 rows
    const int tower = blockIdx.x & 1;              // pair adjacent blocks on one row-tile
    const size_t rowg = (size_t)(blockIdx.x >> 1) * BM;

    // ---- phase 0: x in registers (8 thr/row), LN1 stats, build x-hat ----
    float v[37];
    {
        const float* cr = cum + (rowg + r8)*146;
        const float* ir = inp + (rowg + r8)*136;
        const float* pr = pos + (rowg + r8)*10;
        float s = 0.f, sq = 0.f;
#pragma unroll
        for (int i = 0; i < 37; ++i){
            const int c = p8 + (i << 3);
            float x = 0.f;
            if (c < 292){
                x = (c < 146) ? cr[c] : (c < 282) ? ir[c-146] : pr[c-282];
                s += x; sq += x*x;
            }
            v[i] = x;
        }
        // 8-lane row reduce in-register
#pragma unroll
        for (int off = 1; off <= 4; off <<= 1){ s += __shfl_xor(s, off); sq += __shfl_xor(sq, off); }
        if (p8 == 0){ sRed[r8*2] = s; sRed[r8*2 + 1] = sq; }
        // zero sX cols [292,324) (A reads stop at 320)
#pragma unroll
        for (int j = 0; j < 4; ++j){
            const int c = 292 + p8 + (j << 3);
            if (c < SX) sX[r8*SX + c] = 0;
        }
    }
    __syncthreads();
    if (tid < 64){
        float ss = sRed[tid*2], qq = sRed[tid*2 + 1];
        float m = ss * (1.f/292.f);
        float var = fmaxf(qq * (1.f/292.f) - m*m, 0.f);
        sM[tid] = m; sR[tid] = rsqrtf(var + 1e-5f);
    }
    __syncthreads();
    {
        const float mr = sM[r8], rs = sR[r8];
#pragma unroll
        for (int i = 0; i < 37; ++i){
            const int c = p8 + (i << 3);
            if (c < 292) sX[r8*SX + c] = f2b((v[i] - mr) * rs);
        }
    }
    __syncthreads();

    if (tower == 0){
        // ================= value tower =================
        gemm64ln<10>(sX, SX, wbf + W1_OFF, wf + B1_OFF, sH, sRed, sM, sR, tid);
        __syncthreads();
        gemm64ln<8>(sH, SH, wbf + W2_OFF, wf + B2_OFF, sH, sRed, sM, sR, tid);
        __syncthreads();
        // value head: dot(x-hat3, w3') + B3, 8 threads per row
        const ushort_t* ap = sH + r8*SH + p8*32;
        const float* w3 = wf + W3_OFF + p8*32;
        float s = 0.f;
#pragma unroll
        for (int c = 0; c < 32; ++c) s += b2f(ap[c]) * w3[c];
#pragma unroll
        for (int off = 1; off <= 4; off <<= 1) s += __shfl_xor(s, off);
        if (p8 == 0) sRed[r8] = s;
        __syncthreads();
        if (tid < 64) out[rowg + tid] = sRed[tid] + wf[B3_OFF];
    } else {
        // ================= probability tower =================
        gemm64ln<10>(sX, SX, wbf + P1_OFF, wf + PB1_OFF, sH, sRed, sM, sR, tid);
        __syncthreads();
        gemm64ln<8>(sH, SH, wbf + P2_OFF, wf + PB2_OFF, sH, sRed, sM, sR, tid);
        __syncthreads();
        // score head (256->10) via MFMA on waves 0,1 (32 rows each)
        const int lane = tid & 63, wave = tid >> 6;
        const int l15 = lane & 15, quad = lane >> 4;
        if (wave < 2){
            const int rb = wave*32;
            const ushort_t* ar0 = sH + (rb + l15)*SH + quad*8;
            const ushort_t* ar1 = ar0 + 16*SH;
            const ushort_t* wl = wbf + P3BF_OFF + l15*32 + quad*8;
            floatx4 c0 = (floatx4){0,0,0,0}, c1 = (floatx4){0,0,0,0};
#pragma unroll
            for (int kc = 0; kc < 8; ++kc){
                short8 b  = *(const short8*)(wl + kc*512);
                short8 a0 = *(const short8*)(ar0 + kc*32);
                short8 a1 = *(const short8*)(ar1 + kc*32);
                c0 = __builtin_amdgcn_mfma_f32_16x16x32_bf16(a0, b, c0, 0, 0, 0);
                c1 = __builtin_amdgcn_mfma_f32_16x16x32_bf16(a1, b, c1, 0, 0, 0);
            }
            if (l15 < 10){
                const float bia = wf[PB3_OFF + l15];
#pragma unroll
                for (int i = 0; i < 4; ++i){
                    sScore[(rb + quad*4 + i)*10 + l15]      = c0[i] + bia;
                    sScore[(rb + 16 + quad*4 + i)*10 + l15] = c1[i] + bia;
                }
            }
        }
        __syncthreads();
        if (tid < 64){
            float m = -1e30f;
#pragma unroll
            for (int j = 0; j < 10; ++j) m = fmaxf(m, sScore[tid*10 + j]);
            float l = 0.f;
#pragma unroll
            for (int j = 0; j < 10; ++j) l += expf(sScore[tid*10 + j] - m);
            l = logf(l);
            const size_t rg = rowg + tid;
#pragma unroll
            for (int j = 0; j < 10; ++j){
                const float sv = sScore[tid*10 + j];
                out[(size_t)NROWS    + rg*10 + j] = sv - m - l;
                out[(size_t)NROWS*11 + rg*10 + j] = sv;
            }
        }
    }
}

extern "C" void kernel_launch(void* const* d_in, const int* in_sizes, int n_in,
                              void* d_out, int out_size, void* d_ws, size_t ws_size,
                              hipStream_t stream) {
    (void)in_sizes; (void)n_in; (void)ws_size; (void)out_size;
    const float* cum  = (const float*)d_in[0];
    const float* inp  = (const float*)d_in[1];
    const float* pos  = (const float*)d_in[2];
    const float* ln1w = (const float*)d_in[3];
    const float* ln1b = (const float*)d_in[4];
    const float* ln2w = (const float*)d_in[5];
    const float* ln2b = (const float*)d_in[6];
    const float* ln3w = (const float*)d_in[7];
    const float* ln3b = (const float*)d_in[8];
    const float* n1g  = (const float*)d_in[9];
    const float* n1b  = (const float*)d_in[10];
    const float* n2g  = (const float*)d_in[11];
    const float* n2b  = (const float*)d_in[12];
    const float* n3g  = (const float*)d_in[13];
    const float* n3b  = (const float*)d_in[14];
    const float* p1w  = (const float*)d_in[15];
    const float* p1b  = (const float*)d_in[16];
    const float* p2w  = (const float*)d_in[17];
    const float* p2b  = (const float*)d_in[18];
    const float* p3w  = (const float*)d_in[19];
    const float* p3b  = (const float*)d_in[20];
    const float* pn1g = (const float*)d_in[21];
    const float* pn1b = (const float*)d_in[22];
    const float* pn2g = (const float*)d_in[23];
    const float* pn2b = (const float*)d_in[24];
    const float* pn3g = (const float*)d_in[25];
    const float* pn3b = (const float*)d_in[26];

    ushort_t* wbf = (ushort_t*)d_ws;
    float*    wf  = (float*)((char*)d_ws + BF16_BYTES);
    float*    out = (float*)d_out;

    hipLaunchKernelGGL(bcq_prep, dim3(387), dim3(256), 0, stream,
        ln1w, ln1b, ln2w, ln2b, ln3w, ln3b,
        n1g, n1b, n2g, n2b, n3g, n3b,
        p1w, p1b, p2w, p2b, p3w, p3b,
        pn1g, pn1b, pn2g, pn2b, pn3g, pn3b,
        wbf, wf);

    hipLaunchKernelGGL(bcq_main, dim3((NROWS/BM)*2), dim3(512), 0, stream,
        cum, inp, pos, wbf, wf, out);
}

// Round 3
// 409.070 us; speedup vs baseline: 1.3698x; 1.3698x over previous
//
#include <hip/hip_runtime.h>

typedef unsigned short ushort_t;
typedef unsigned int   uint_t;
typedef __attribute__((ext_vector_type(8))) short  short8;
typedef __attribute__((ext_vector_type(4))) float  floatx4;

#define NROWS 131072
#define BM    32
#define SX    328     // x-hat bf16 LDS row stride (ushorts); cols >=292 zeroed to 320
#define SH    264     // h bf16 LDS row stride (ushorts)

// d_ws bf16 region (ushort element offsets) — chunk-major: [kc][col(256)][k(32)]
#define W1_OFF 0        // 10 chunks
#define P1_OFF 81920    // 10 chunks
#define W2_OFF 163840   // 8 chunks
#define P2_OFF 229376   // 8 chunks
#define P3BF_OFF 294912 // 8 chunks x [16 cols][32] bf16 frag layout (cols>=10 zero)
#define BF16_BYTES 598016
// d_ws float region (float element offsets, base = ws + BF16_BYTES)
#define B1_OFF  0
#define PB1_OFF 256
#define B2_OFF  512
#define PB2_OFF 768
#define W3_OFF  1024
#define B3_OFF  3840
#define PB3_OFF 3841

__device__ __forceinline__ float b2f(ushort_t u){
    union { uint_t i; float f; } v; v.i = ((uint_t)u) << 16; return v.f;
}
__device__ __forceinline__ ushort_t f2b(float f){
    union { uint_t i; float f; } v; v.f = f;
    uint_t b = v.i;
    b += 0x7FFFu + ((b >> 16) & 1u);   // RNE
    return (ushort_t)(b >> 16);
}

// ---------------- prologue: fold LN gain/bias into linears, fp32 -> bf16 ----
__global__ __launch_bounds__(256) void bcq_prep(
    const float* __restrict__ ln1w, const float* __restrict__ ln1b,
    const float* __restrict__ ln2w, const float* __restrict__ ln2b,
    const float* __restrict__ ln3w, const float* __restrict__ ln3b,
    const float* __restrict__ n1g,  const float* __restrict__ n1b,
    const float* __restrict__ n2g,  const float* __restrict__ n2b,
    const float* __restrict__ n3g,  const float* __restrict__ n3b,
    const float* __restrict__ p1w,  const float* __restrict__ p1b,
    const float* __restrict__ p2w,  const float* __restrict__ p2b,
    const float* __restrict__ p3w,  const float* __restrict__ p3b,
    const float* __restrict__ pn1g, const float* __restrict__ pn1b,
    const float* __restrict__ pn2g, const float* __restrict__ pn2b,
    const float* __restrict__ pn3g, const float* __restrict__ pn3b,
    ushort_t* __restrict__ wbf, float* __restrict__ wf)
{
    const int bid = blockIdx.x, tid = threadIdx.x;
    if (bid < 128){
        // layer 1 (K=292 padded to 320): W1 then P1
        for (int i = bid*256 + tid; i < 163840; i += 128*256){
            const int which = i / 81920;            // 0=W1, 1=P1
            const int r  = i - which*81920;
            const int kc = r >> 13;                  // /8192
            const int t  = r & 8191;
            const int c  = t >> 5, kk = t & 31;
            const int k  = kc*32 + kk;
            const float* src = which ? p1w  : ln1w;
            const float* g   = which ? pn1g : n1g;
            ushort_t v = 0;
            if (k < 292) v = f2b(src[c*292 + k] * g[k]);
            wbf[i] = v;
        }
        // layer 2 (K=256): W2 then P2
        for (int i = bid*256 + tid; i < 131072; i += 128*256){
            const int which = i >> 16;
            const int r  = i & 65535;
            const int kc = r >> 13;
            const int t  = r & 8191;
            const int c  = t >> 5, kk = t & 31;
            const int k  = kc*32 + kk;
            const float* src = which ? p2w  : ln2w;
            const float* g   = which ? pn2g : n2g;
            wbf[W2_OFF + i] = f2b(src[c*256 + k] * g[k]);
        }
    } else if (bid < 384){
        const int d = (bid - 128)*4 + (tid >> 6);
        const int lane = tid & 63;
        const float *w, *nb, *bs; int K, outoff; const int c = d & 255;
        if (d < 256)      { w = ln1w; nb = n1b;  bs = ln1b; K = 292; outoff = B1_OFF; }
        else if (d < 512) { w = p1w;  nb = pn1b; bs = p1b;  K = 292; outoff = PB1_OFF; }
        else if (d < 768) { w = ln2w; nb = n2b;  bs = ln2b; K = 256; outoff = B2_OFF; }
        else              { w = p2w;  nb = pn2b; bs = p2b;  K = 256; outoff = PB2_OFF; }
        float s = 0.f;
        for (int k = lane; k < K; k += 64) s += w[c*K + k] * nb[k];
        for (int off = 32; off; off >>= 1) s += __shfl_down(s, off);
        if (lane == 0) wf[outoff + c] = s + bs[c];
    } else if (bid == 384){
        wf[W3_OFF + tid] = ln3w[tid] * n3g[tid];
        // P3 in bf16 MFMA B-frag layout: [kc][col(16)][kk(32)], cols >=10 zero
        for (int i = tid; i < 4096; i += 256){
            const int kc = i >> 9, t = i & 511, c = t >> 5, kk = t & 31;
            const int k = kc*32 + kk;
            ushort_t vv = 0;
            if (c < 10) vv = f2b(p3w[c*256 + k] * pn3g[k]);
            wbf[P3BF_OFF + i] = vv;
        }
    } else {
        const int g32 = tid >> 5, l32 = tid & 31;
        const int d = (bid - 385)*8 + g32;                   // valid < 11
        if (d < 11){
            const float* w  = (d == 0) ? ln3w : (p3w + (d-1)*256);
            const float* nb = (d == 0) ? n3b  : pn3b;
            float s = 0.f;
            for (int k = l32; k < 256; k += 32) s += w[k] * nb[k];
            for (int off = 16; off; off >>= 1) s += __shfl_xor(s, off);
            if (l32 == 0){
                if (d == 0) wf[B3_OFF] = s + ln3b[0];
                else        wf[PB3_OFF + d - 1] = s + p3b[d - 1];
            }
        }
    }
}

// ---------------- main ------------------------------------------------------
// GEMM: y[32x256] = relu(sIn @ W'^T + b'); fused LN epilogue writes
// normalized x-hat bf16 to sOut directly (stats from registers, shuffle-reduced).
// Safe for sOut aliasing sIn: all sIn reads complete before the two internal
// barriers that precede the sOut writes.
template<int FULLKC>
__device__ __forceinline__ void gemm32ln(
    const ushort_t* sIn, int astride, const ushort_t* __restrict__ Wg,
    const float* __restrict__ biasf, ushort_t* sOut,
    float* sRed, float* sM, float* sR, int tid)
{
    const int lane = tid & 63, wave = tid >> 6;
    const int l15 = lane & 15, quad = lane >> 4;
    const int colbase = wave * 64;
    const ushort_t* ar0 = sIn + l15*astride + quad*8;
    const ushort_t* ar1 = ar0 + 16*astride;
    // chunk-major: frag addr = (colbase + nt*16 + l15)*32 + quad*8 + kc*8192
    const ushort_t* wl = Wg + (colbase + l15)*32 + quad*8;

    floatx4 acc[4][2];
#pragma unroll
    for (int nt = 0; nt < 4; ++nt){ acc[nt][0] = (floatx4){0,0,0,0}; acc[nt][1] = (floatx4){0,0,0,0}; }

    short8 bb0[4], bb1[4];
#pragma unroll
    for (int nt = 0; nt < 4; ++nt) bb0[nt] = *(const short8*)(wl + nt*512);
#pragma unroll
    for (int nt = 0; nt < 4; ++nt) bb1[nt] = *(const short8*)(wl + nt*512 + 8192);

#pragma unroll
    for (int kc = 0; kc < FULLKC; ++kc){
        short8 bnew[4];
        if (kc + 2 < FULLKC){
#pragma unroll
            for (int nt = 0; nt < 4; ++nt)
                bnew[nt] = *(const short8*)(wl + nt*512 + (kc + 2)*8192);
        }
        short8 a0 = *(const short8*)(ar0 + kc*32);
        short8 a1 = *(const short8*)(ar1 + kc*32);
#pragma unroll
        for (int nt = 0; nt < 4; ++nt){
            const short8 bc = (kc & 1) ? bb1[nt] : bb0[nt];
            acc[nt][0] = __builtin_amdgcn_mfma_f32_16x16x32_bf16(a0, bc, acc[nt][0], 0, 0, 0);
            acc[nt][1] = __builtin_amdgcn_mfma_f32_16x16x32_bf16(a1, bc, acc[nt][1], 0, 0, 0);
        }
        if (kc + 2 < FULLKC){
#pragma unroll
            for (int nt = 0; nt < 4; ++nt){
                if (kc & 1) bb1[nt] = bnew[nt]; else bb0[nt] = bnew[nt];
            }
        }
    }

    // ---- fused LN epilogue ----
    float bia[4];
#pragma unroll
    for (int nt = 0; nt < 4; ++nt) bia[nt] = biasf[colbase + nt*16 + l15];

    // per-(s2,i) row partials over this wave's 4 col-tiles
    float ps[2][4], pq[2][4];
#pragma unroll
    for (int s2 = 0; s2 < 2; ++s2)
#pragma unroll
        for (int i = 0; i < 4; ++i){
            float s = 0.f, q = 0.f;
#pragma unroll
            for (int nt = 0; nt < 4; ++nt){
                float y = fmaxf(acc[nt][s2][i] + bia[nt], 0.f);
                s += y; q += y*y;
            }
            ps[s2][i] = s; pq[s2][i] = q;
        }
    // reduce across the 16 lanes of the quad (cols)
#pragma unroll
    for (int off = 1; off <= 8; off <<= 1){
#pragma unroll
        for (int s2 = 0; s2 < 2; ++s2)
#pragma unroll
            for (int i = 0; i < 4; ++i){
                ps[s2][i] += __shfl_xor(ps[s2][i], off);
                pq[s2][i] += __shfl_xor(pq[s2][i], off);
            }
    }
    if (l15 == 0){
#pragma unroll
        for (int s2 = 0; s2 < 2; ++s2)
#pragma unroll
            for (int i = 0; i < 4; ++i){
                const int row = s2*16 + quad*4 + i;
                sRed[row*8 + wave*2 + 0] = ps[s2][i];
                sRed[row*8 + wave*2 + 1] = pq[s2][i];
            }
    }
    __syncthreads();
    if (tid < 32){
        float ss = 0.f, qq = 0.f;
#pragma unroll
        for (int w = 0; w < 4; ++w){ ss += sRed[tid*8 + w*2]; qq += sRed[tid*8 + w*2 + 1]; }
        float m = ss * (1.f/256.f);
        float var = fmaxf(qq * (1.f/256.f) - m*m, 0.f);
        sM[tid] = m; sR[tid] = rsqrtf(var + 1e-5f);
    }
    __syncthreads();
    // normalize from registers, write bf16 x-hat (sOut may alias sIn — safe now)
#pragma unroll
    for (int s2 = 0; s2 < 2; ++s2)
#pragma unroll
        for (int i = 0; i < 4; ++i){
            const int row = s2*16 + quad*4 + i;
            const float m = sM[row], r = sR[row];
#pragma unroll
            for (int nt = 0; nt < 4; ++nt){
                float y = fmaxf(acc[nt][s2][i] + bia[nt], 0.f);
                sOut[row*SH + colbase + nt*16 + l15] = f2b((y - m) * r);
            }
        }
}

__global__ __launch_bounds__(256)
__attribute__((amdgpu_waves_per_eu(4, 4)))   // 128-VGPR budget: working set (~95) fits, NO SPILL
void bcq_main(
    const float* __restrict__ cum, const float* __restrict__ inp, const float* __restrict__ pos,
    const ushort_t* __restrict__ wbf, const float* __restrict__ wf, float* __restrict__ out)
{
    // 22528 B LDS; x-hat buffer aliased by h buffer
    __shared__ __align__(16) char sMem[22528];
    ushort_t* sX     = (ushort_t*)sMem;            // 20992 B: x-hat (stride SX)
    ushort_t* sH     = (ushort_t*)sMem;            // alias:   h     (stride SH, 16896 B)
    float*    sRed   = (float*)(sMem + 20992);     // 1280 B scratch (score buf aliases)
    float*    sScore = sRed;
    float*    sM     = (float*)(sMem + 22272);     // 128 B
    float*    sR     = (float*)(sMem + 22400);     // 128 B

    const int tid = threadIdx.x;
    const int r8 = tid >> 3, p8 = tid & 7;
    const int tower = blockIdx.x & 1;              // pair adjacent blocks on one row-tile
    const size_t rowg = (size_t)(blockIdx.x >> 1) * BM;

    // ---- phase 0: x in registers (8 thr/row), LN1 stats, build x-hat ----
    float v[37];
    {
        const float* cr = cum + (rowg + r8)*146;
        const float* ir = inp + (rowg + r8)*136;
        const float* pr = pos + (rowg + r8)*10;
        float s = 0.f, sq = 0.f;
#pragma unroll
        for (int i = 0; i < 37; ++i){
            const int c = p8 + (i << 3);
            float x = 0.f;
            if (c < 292){
                x = (c < 146) ? cr[c] : (c < 282) ? ir[c-146] : pr[c-282];
                s += x; sq += x*x;
            }
            v[i] = x;
        }
        // 8-lane row reduce in-register
#pragma unroll
        for (int off = 1; off <= 4; off <<= 1){ s += __shfl_xor(s, off); sq += __shfl_xor(sq, off); }
        if (p8 == 0){ sRed[r8*2] = s; sRed[r8*2 + 1] = sq; }
        // zero sX cols [292,324) (A reads stop at 320)
#pragma unroll
        for (int j = 0; j < 4; ++j){
            const int c = 292 + p8 + (j << 3);
            if (c < SX) sX[r8*SX + c] = 0;
        }
    }
    __syncthreads();
    if (tid < 32){
        float ss = sRed[tid*2], qq = sRed[tid*2 + 1];
        float m = ss * (1.f/292.f);
        float var = fmaxf(qq * (1.f/292.f) - m*m, 0.f);
        sM[tid] = m; sR[tid] = rsqrtf(var + 1e-5f);
    }
    __syncthreads();
    {
        const float mr = sM[r8], rs = sR[r8];
#pragma unroll
        for (int i = 0; i < 37; ++i){
            const int c = p8 + (i << 3);
            if (c < 292) sX[r8*SX + c] = f2b((v[i] - mr) * rs);
        }
    }
    __syncthreads();

    if (tower == 0){
        // ================= value tower =================
        gemm32ln<10>(sX, SX, wbf + W1_OFF, wf + B1_OFF, sH, sRed, sM, sR, tid);
        __syncthreads();
        gemm32ln<8>(sH, SH, wbf + W2_OFF, wf + B2_OFF, sH, sRed, sM, sR, tid);
        __syncthreads();
        // value head: dot(x-hat3, w3') + B3
        const ushort_t* ap = sH + r8*SH + p8*32;
        const float* w3 = wf + W3_OFF + p8*32;
        float s = 0.f;
#pragma unroll
        for (int c = 0; c < 32; ++c) s += b2f(ap[c]) * w3[c];
#pragma unroll
        for (int off = 1; off <= 4; off <<= 1) s += __shfl_xor(s, off);
        if (p8 == 0) sRed[r8] = s;
        __syncthreads();
        if (tid < 32) out[rowg + tid] = sRed[tid] + wf[B3_OFF];
    } else {
        // ================= probability tower =================
        gemm32ln<10>(sX, SX, wbf + P1_OFF, wf + PB1_OFF, sH, sRed, sM, sR, tid);
        __syncthreads();
        gemm32ln<8>(sH, SH, wbf + P2_OFF, wf + PB2_OFF, sH, sRed, sM, sR, tid);
        __syncthreads();
        // score head (256->10) via MFMA on wave 0: C[row, col=l15<10]
        const int lane = tid & 63, wave = tid >> 6;
        const int l15 = lane & 15, quad = lane >> 4;
        if (wave == 0){
            const ushort_t* ar0 = sH + l15*SH + quad*8;
            const ushort_t* ar1 = ar0 + 16*SH;
            const ushort_t* wl = wbf + P3BF_OFF + l15*32 + quad*8;
            floatx4 c0 = (floatx4){0,0,0,0}, c1 = (floatx4){0,0,0,0};
#pragma unroll
            for (int kc = 0; kc < 8; ++kc){
                short8 b  = *(const short8*)(wl + kc*512);
                short8 a0 = *(const short8*)(ar0 + kc*32);
                short8 a1 = *(const short8*)(ar1 + kc*32);
                c0 = __builtin_amdgcn_mfma_f32_16x16x32_bf16(a0, b, c0, 0, 0, 0);
                c1 = __builtin_amdgcn_mfma_f32_16x16x32_bf16(a1, b, c1, 0, 0, 0);
            }
            if (l15 < 10){
                const float bia = wf[PB3_OFF + l15];
#pragma unroll
                for (int i = 0; i < 4; ++i){
                    sScore[(quad*4 + i)*10 + l15]      = c0[i] + bia;
                    sScore[(16 + quad*4 + i)*10 + l15] = c1[i] + bia;
                }
            }
        }
        __syncthreads();
        if (tid < 32){
            float m = -1e30f;
#pragma unroll
            for (int j = 0; j < 10; ++j) m = fmaxf(m, sScore[tid*10 + j]);
            float l = 0.f;
#pragma unroll
            for (int j = 0; j < 10; ++j) l += expf(sScore[tid*10 + j] - m);
            l = logf(l);
            const size_t rg = rowg + tid;
#pragma unroll
            for (int j = 0; j < 10; ++j){
                const float sv = sScore[tid*10 + j];
                out[(size_t)NROWS    + rg*10 + j] = sv - m - l;
                out[(size_t)NROWS*11 + rg*10 + j] = sv;
            }
        }
    }
}

extern "C" void kernel_launch(void* const* d_in, const int* in_sizes, int n_in,
                              void* d_out, int out_size, void* d_ws, size_t ws_size,
                              hipStream_t stream) {
    (void)in_sizes; (void)n_in; (void)ws_size; (void)out_size;
    const float* cum  = (const float*)d_in[0];
    const float* inp  = (const float*)d_in[1];
    const float* pos  = (const float*)d_in[2];
    const float* ln1w = (const float*)d_in[3];
    const float* ln1b = (const float*)d_in[4];
    const float* ln2w = (const float*)d_in[5];
    const float* ln2b = (const float*)d_in[6];
    const float* ln3w = (const float*)d_in[7];
    const float* ln3b = (const float*)d_in[8];
    const float* n1g  = (const float*)d_in[9];
    const float* n1b  = (const float*)d_in[10];
    const float* n2g  = (const float*)d_in[11];
    const float* n2b  = (const float*)d_in[12];
    const float* n3g  = (const float*)d_in[13];
    const float* n3b  = (const float*)d_in[14];
    const float* p1w  = (const float*)d_in[15];
    const float* p1b  = (const float*)d_in[16];
    const float* p2w  = (const float*)d_in[17];
    const float* p2b  = (const float*)d_in[18];
    const float* p3w  = (const float*)d_in[19];
    const float* p3b  = (const float*)d_in[20];
    const float* pn1g = (const float*)d_in[21];
    const float* pn1b = (const float*)d_in[22];
    const float* pn2g = (const float*)d_in[23];
    const float* pn2b = (const float*)d_in[24];
    const float* pn3g = (const float*)d_in[25];
    const float* pn3b = (const float*)d_in[26];

    ushort_t* wbf = (ushort_t*)d_ws;
    float*    wf  = (float*)((char*)d_ws + BF16_BYTES);
    float*    out = (float*)d_out;

    hipLaunchKernelGGL(bcq_prep, dim3(387), dim3(256), 0, stream,
        ln1w, ln1b, ln2w, ln2b, ln3w, ln3b,
        n1g, n1b, n2g, n2b, n3g, n3b,
        p1w, p1b, p2w, p2b, p3w, p3b,
        pn1g, pn1b, pn2g, pn2b, pn3g, pn3b,
        wbf, wf);

    hipLaunchKernelGGL(bcq_main, dim3((NROWS/BM)*2), dim3(256), 0, stream,
        cum, inp, pos, wbf, wf, out);
}

// Round 4
// 387.207 us; speedup vs baseline: 1.4471x; 1.0565x over previous
//
#include <hip/hip_runtime.h>

typedef unsigned short ushort_t;
typedef unsigned int   uint_t;
typedef __attribute__((ext_vector_type(8))) short  short8;
typedef __attribute__((ext_vector_type(4))) float  floatx4;

#define NROWS 131072
#define BM    32
#define SX    328     // x-hat bf16 LDS row stride (ushorts); cols >=292 zeroed to 320
#define SH    264     // h bf16 LDS row stride (ushorts)

// d_ws bf16 region (ushort element offsets) — chunk-major: [kc][col(256)][k(32)]
#define W1_OFF 0        // 10 chunks
#define P1_OFF 81920    // 10 chunks
#define W2_OFF 163840   // 8 chunks
#define P2_OFF 229376   // 8 chunks
#define P3BF_OFF 294912 // 8 chunks x [16 cols][32] bf16 frag layout (cols>=10 zero)
#define BF16_BYTES 598016
// d_ws float region (float element offsets, base = ws + BF16_BYTES)
#define B1_OFF  0
#define PB1_OFF 256
#define B2_OFF  512
#define PB2_OFF 768
#define W3_OFF  1024
#define B3_OFF  3840
#define PB3_OFF 3841

__device__ __forceinline__ float b2f(ushort_t u){
    union { uint_t i; float f; } v; v.i = ((uint_t)u) << 16; return v.f;
}
__device__ __forceinline__ ushort_t f2b(float f){
    union { uint_t i; float f; } v; v.f = f;
    uint_t b = v.i;
    b += 0x7FFFu + ((b >> 16) & 1u);   // RNE
    return (ushort_t)(b >> 16);
}

// ---------------- prologue: fold LN gain/bias into linears, fp32 -> bf16 ----
__global__ __launch_bounds__(256) void bcq_prep(
    const float* __restrict__ ln1w, const float* __restrict__ ln1b,
    const float* __restrict__ ln2w, const float* __restrict__ ln2b,
    const float* __restrict__ ln3w, const float* __restrict__ ln3b,
    const float* __restrict__ n1g,  const float* __restrict__ n1b,
    const float* __restrict__ n2g,  const float* __restrict__ n2b,
    const float* __restrict__ n3g,  const float* __restrict__ n3b,
    const float* __restrict__ p1w,  const float* __restrict__ p1b,
    const float* __restrict__ p2w,  const float* __restrict__ p2b,
    const float* __restrict__ p3w,  const float* __restrict__ p3b,
    const float* __restrict__ pn1g, const float* __restrict__ pn1b,
    const float* __restrict__ pn2g, const float* __restrict__ pn2b,
    const float* __restrict__ pn3g, const float* __restrict__ pn3b,
    ushort_t* __restrict__ wbf, float* __restrict__ wf)
{
    const int bid = blockIdx.x, tid = threadIdx.x;
    if (bid < 128){
        // layer 1 (K=292 padded to 320): W1 then P1
        for (int i = bid*256 + tid; i < 163840; i += 128*256){
            const int which = i / 81920;            // 0=W1, 1=P1
            const int r  = i - which*81920;
            const int kc = r >> 13;                  // /8192
            const int t  = r & 8191;
            const int c  = t >> 5, kk = t & 31;
            const int k  = kc*32 + kk;
            const float* src = which ? p1w  : ln1w;
            const float* g   = which ? pn1g : n1g;
            ushort_t v = 0;
            if (k < 292) v = f2b(src[c*292 + k] * g[k]);
            wbf[i] = v;
        }
        // layer 2 (K=256): W2 then P2
        for (int i = bid*256 + tid; i < 131072; i += 128*256){
            const int which = i >> 16;
            const int r  = i & 65535;
            const int kc = r >> 13;
            const int t  = r & 8191;
            const int c  = t >> 5, kk = t & 31;
            const int k  = kc*32 + kk;
            const float* src = which ? p2w  : ln2w;
            const float* g   = which ? pn2g : n2g;
            wbf[W2_OFF + i] = f2b(src[c*256 + k] * g[k]);
        }
    } else if (bid < 384){
        const int d = (bid - 128)*4 + (tid >> 6);
        const int lane = tid & 63;
        const float *w, *nb, *bs; int K, outoff; const int c = d & 255;
        if (d < 256)      { w = ln1w; nb = n1b;  bs = ln1b; K = 292; outoff = B1_OFF; }
        else if (d < 512) { w = p1w;  nb = pn1b; bs = p1b;  K = 292; outoff = PB1_OFF; }
        else if (d < 768) { w = ln2w; nb = n2b;  bs = ln2b; K = 256; outoff = B2_OFF; }
        else              { w = p2w;  nb = pn2b; bs = p2b;  K = 256; outoff = PB2_OFF; }
        float s = 0.f;
        for (int k = lane; k < K; k += 64) s += w[c*K + k] * nb[k];
        for (int off = 32; off; off >>= 1) s += __shfl_down(s, off);
        if (lane == 0) wf[outoff + c] = s + bs[c];
    } else if (bid == 384){
        wf[W3_OFF + tid] = ln3w[tid] * n3g[tid];
        // P3 in bf16 MFMA B-frag layout: [kc][col(16)][kk(32)], cols >=10 zero
        for (int i = tid; i < 4096; i += 256){
            const int kc = i >> 9, t = i & 511, c = t >> 5, kk = t & 31;
            const int k = kc*32 + kk;
            ushort_t vv = 0;
            if (c < 10) vv = f2b(p3w[c*256 + k] * pn3g[k]);
            wbf[P3BF_OFF + i] = vv;
        }
    } else {
        const int g32 = tid >> 5, l32 = tid & 31;
        const int d = (bid - 385)*8 + g32;                   // valid < 11
        if (d < 11){
            const float* w  = (d == 0) ? ln3w : (p3w + (d-1)*256);
            const float* nb = (d == 0) ? n3b  : pn3b;
            float s = 0.f;
            for (int k = l32; k < 256; k += 32) s += w[k] * nb[k];
            for (int off = 16; off; off >>= 1) s += __shfl_xor(s, off);
            if (l32 == 0){
                if (d == 0) wf[B3_OFF] = s + ln3b[0];
                else        wf[PB3_OFF + d - 1] = s + p3b[d - 1];
            }
        }
    }
}

// ---------------- main ------------------------------------------------------
// GEMM: y[32x256] = relu(sIn @ W'^T + b'); fused LN epilogue writes
// normalized x-hat bf16 to sOut directly (stats from registers, shuffle-reduced).
// Safe for sOut aliasing sIn: all sIn reads complete before the two internal
// barriers that precede the sOut writes.
template<int FULLKC>
__device__ __forceinline__ void gemm32ln(
    const ushort_t* sIn, int astride, const ushort_t* __restrict__ Wg,
    const float* __restrict__ biasf, ushort_t* sOut,
    float* sRed, float* sM, float* sR, int tid)
{
    const int lane = tid & 63, wave = tid >> 6;
    const int l15 = lane & 15, quad = lane >> 4;
    const int colbase = wave * 64;
    const ushort_t* ar0 = sIn + l15*astride + quad*8;
    const ushort_t* ar1 = ar0 + 16*astride;
    // chunk-major: frag addr = (colbase + nt*16 + l15)*32 + quad*8 + kc*8192
    const ushort_t* wl = Wg + (colbase + l15)*32 + quad*8;

    floatx4 acc[4][2];
#pragma unroll
    for (int nt = 0; nt < 4; ++nt){ acc[nt][0] = (floatx4){0,0,0,0}; acc[nt][1] = (floatx4){0,0,0,0}; }

    short8 bb0[4], bb1[4];
#pragma unroll
    for (int nt = 0; nt < 4; ++nt) bb0[nt] = *(const short8*)(wl + nt*512);
#pragma unroll
    for (int nt = 0; nt < 4; ++nt) bb1[nt] = *(const short8*)(wl + nt*512 + 8192);

#pragma unroll
    for (int kc = 0; kc < FULLKC; ++kc){
        short8 bnew[4];
        if (kc + 2 < FULLKC){
#pragma unroll
            for (int nt = 0; nt < 4; ++nt)
                bnew[nt] = *(const short8*)(wl + nt*512 + (kc + 2)*8192);
        }
        short8 a0 = *(const short8*)(ar0 + kc*32);
        short8 a1 = *(const short8*)(ar1 + kc*32);
#pragma unroll
        for (int nt = 0; nt < 4; ++nt){
            const short8 bc = (kc & 1) ? bb1[nt] : bb0[nt];
            acc[nt][0] = __builtin_amdgcn_mfma_f32_16x16x32_bf16(a0, bc, acc[nt][0], 0, 0, 0);
            acc[nt][1] = __builtin_amdgcn_mfma_f32_16x16x32_bf16(a1, bc, acc[nt][1], 0, 0, 0);
        }
        if (kc + 2 < FULLKC){
#pragma unroll
            for (int nt = 0; nt < 4; ++nt){
                if (kc & 1) bb1[nt] = bnew[nt]; else bb0[nt] = bnew[nt];
            }
        }
    }

    // ---- fused LN epilogue ----
    float bia[4];
#pragma unroll
    for (int nt = 0; nt < 4; ++nt) bia[nt] = biasf[colbase + nt*16 + l15];

    // per-(s2,i) row partials over this wave's 4 col-tiles
    float ps[2][4], pq[2][4];
#pragma unroll
    for (int s2 = 0; s2 < 2; ++s2)
#pragma unroll
        for (int i = 0; i < 4; ++i){
            float s = 0.f, q = 0.f;
#pragma unroll
            for (int nt = 0; nt < 4; ++nt){
                float y = fmaxf(acc[nt][s2][i] + bia[nt], 0.f);
                s += y; q += y*y;
            }
            ps[s2][i] = s; pq[s2][i] = q;
        }
    // reduce across the 16 lanes of the quad (cols)
#pragma unroll
    for (int off = 1; off <= 8; off <<= 1){
#pragma unroll
        for (int s2 = 0; s2 < 2; ++s2)
#pragma unroll
            for (int i = 0; i < 4; ++i){
                ps[s2][i] += __shfl_xor(ps[s2][i], off);
                pq[s2][i] += __shfl_xor(pq[s2][i], off);
            }
    }
    if (l15 == 0){
#pragma unroll
        for (int s2 = 0; s2 < 2; ++s2)
#pragma unroll
            for (int i = 0; i < 4; ++i){
                const int row = s2*16 + quad*4 + i;
                sRed[row*8 + wave*2 + 0] = ps[s2][i];
                sRed[row*8 + wave*2 + 1] = pq[s2][i];
            }
    }
    __syncthreads();
    if (tid < 32){
        float ss = 0.f, qq = 0.f;
#pragma unroll
        for (int w = 0; w < 4; ++w){ ss += sRed[tid*8 + w*2]; qq += sRed[tid*8 + w*2 + 1]; }
        float m = ss * (1.f/256.f);
        float var = fmaxf(qq * (1.f/256.f) - m*m, 0.f);
        sM[tid] = m; sR[tid] = rsqrtf(var + 1e-5f);
    }
    __syncthreads();
    // normalize from registers, write bf16 x-hat (sOut may alias sIn — safe now)
#pragma unroll
    for (int s2 = 0; s2 < 2; ++s2)
#pragma unroll
        for (int i = 0; i < 4; ++i){
            const int row = s2*16 + quad*4 + i;
            const float m = sM[row], r = sR[row];
#pragma unroll
            for (int nt = 0; nt < 4; ++nt){
                float y = fmaxf(acc[nt][s2][i] + bia[nt], 0.f);
                sOut[row*SH + colbase + nt*16 + l15] = f2b((y - m) * r);
            }
        }
}

__global__ __launch_bounds__(256)
__attribute__((amdgpu_waves_per_eu(4, 8)))   // min 4 -> 128-VGPR budget; allow 5+ waves/EU if regs permit
void bcq_main(
    const float* __restrict__ cum, const float* __restrict__ inp, const float* __restrict__ pos,
    const ushort_t* __restrict__ wbf, const float* __restrict__ wf, float* __restrict__ out)
{
    // 22528 B LDS; x-hat buffer aliased by h buffer
    __shared__ __align__(16) char sMem[22528];
    ushort_t* sX     = (ushort_t*)sMem;            // 20992 B: x-hat (stride SX)
    ushort_t* sH     = (ushort_t*)sMem;            // alias:   h     (stride SH, 16896 B)
    float*    sRed   = (float*)(sMem + 20992);     // 1280 B scratch (score buf aliases)
    float*    sScore = sRed;
    float*    sM     = (float*)(sMem + 22272);     // 128 B
    float*    sR     = (float*)(sMem + 22400);     // 128 B

    const int tid = threadIdx.x;
    const int r8 = tid >> 3, p8 = tid & 7;
    const int tower = blockIdx.x & 1;              // pair adjacent blocks on one row-tile
    const size_t rowg = (size_t)(blockIdx.x >> 1) * BM;

    const float* cr = cum + (rowg + r8)*146;
    const float* ir = inp + (rowg + r8)*136;
    const float* pr = pos + (rowg + r8)*10;

    // ---- phase 0, pass 1: LN1 stats ONLY — x is not kept live across barriers
    {
        float s = 0.f, sq = 0.f;
#pragma unroll
        for (int i = 0; i < 37; ++i){
            const int c = p8 + (i << 3);
            if (c < 292){
                float x = (c < 146) ? cr[c] : (c < 282) ? ir[c-146] : pr[c-282];
                s += x; sq += x*x;
            }
        }
        // 8-lane row reduce in-register
#pragma unroll
        for (int off = 1; off <= 4; off <<= 1){ s += __shfl_xor(s, off); sq += __shfl_xor(sq, off); }
        if (p8 == 0){ sRed[r8*2] = s; sRed[r8*2 + 1] = sq; }
        // zero sX cols [292,324) (A reads stop at 320)
#pragma unroll
        for (int j = 0; j < 4; ++j){
            const int c = 292 + p8 + (j << 3);
            if (c < SX) sX[r8*SX + c] = 0;
        }
    }
    __syncthreads();
    if (tid < 32){
        float ss = sRed[tid*2], qq = sRed[tid*2 + 1];
        float m = ss * (1.f/292.f);
        float var = fmaxf(qq * (1.f/292.f) - m*m, 0.f);
        sM[tid] = m; sR[tid] = rsqrtf(var + 1e-5f);
    }
    __syncthreads();
    // Force re-load of x (L1/L2-hot) instead of carrying 37 floats across the
    // barriers — that live range was spilling ~16 dwords/thread to scratch
    // (the 126 MB excess WRITE_SIZE seen in rounds 1-3).
    asm volatile("" ::: "memory");
    // ---- phase 0, pass 2: reload x, normalize, store bf16 x-hat ----
    {
        const float mr = sM[r8], rs = sR[r8];
#pragma unroll
        for (int i = 0; i < 37; ++i){
            const int c = p8 + (i << 3);
            if (c < 292){
                float x = (c < 146) ? cr[c] : (c < 282) ? ir[c-146] : pr[c-282];
                sX[r8*SX + c] = f2b((x - mr) * rs);
            }
        }
    }
    __syncthreads();

    if (tower == 0){
        // ================= value tower =================
        gemm32ln<10>(sX, SX, wbf + W1_OFF, wf + B1_OFF, sH, sRed, sM, sR, tid);
        __syncthreads();
        gemm32ln<8>(sH, SH, wbf + W2_OFF, wf + B2_OFF, sH, sRed, sM, sR, tid);
        __syncthreads();
        // value head: dot(x-hat3, w3') + B3
        const ushort_t* ap = sH + r8*SH + p8*32;
        const float* w3 = wf + W3_OFF + p8*32;
        float s = 0.f;
#pragma unroll
        for (int c = 0; c < 32; ++c) s += b2f(ap[c]) * w3[c];
#pragma unroll
        for (int off = 1; off <= 4; off <<= 1) s += __shfl_xor(s, off);
        if (p8 == 0) sRed[r8] = s;
        __syncthreads();
        if (tid < 32) out[rowg + tid] = sRed[tid] + wf[B3_OFF];
    } else {
        // ================= probability tower =================
        gemm32ln<10>(sX, SX, wbf + P1_OFF, wf + PB1_OFF, sH, sRed, sM, sR, tid);
        __syncthreads();
        gemm32ln<8>(sH, SH, wbf + P2_OFF, wf + PB2_OFF, sH, sRed, sM, sR, tid);
        __syncthreads();
        // score head (256->10) via MFMA on wave 0: C[row, col=l15<10]
        const int lane = tid & 63, wave = tid >> 6;
        const int l15 = lane & 15, quad = lane >> 4;
        if (wave == 0){
            const ushort_t* ar0 = sH + l15*SH + quad*8;
            const ushort_t* ar1 = ar0 + 16*SH;
            const ushort_t* wl = wbf + P3BF_OFF + l15*32 + quad*8;
            floatx4 c0 = (floatx4){0,0,0,0}, c1 = (floatx4){0,0,0,0};
#pragma unroll
            for (int kc = 0; kc < 8; ++kc){
                short8 b  = *(const short8*)(wl + kc*512);
                short8 a0 = *(const short8*)(ar0 + kc*32);
                short8 a1 = *(const short8*)(ar1 + kc*32);
                c0 = __builtin_amdgcn_mfma_f32_16x16x32_bf16(a0, b, c0, 0, 0, 0);
                c1 = __builtin_amdgcn_mfma_f32_16x16x32_bf16(a1, b, c1, 0, 0, 0);
            }
            if (l15 < 10){
                const float bia = wf[PB3_OFF + l15];
#pragma unroll
                for (int i = 0; i < 4; ++i){
                    sScore[(quad*4 + i)*10 + l15]      = c0[i] + bia;
                    sScore[(16 + quad*4 + i)*10 + l15] = c1[i] + bia;
                }
            }
        }
        __syncthreads();
        if (tid < 32){
            float m = -1e30f;
#pragma unroll
            for (int j = 0; j < 10; ++j) m = fmaxf(m, sScore[tid*10 + j]);
            float l = 0.f;
#pragma unroll
            for (int j = 0; j < 10; ++j) l += expf(sScore[tid*10 + j] - m);
            l = logf(l);
            const size_t rg = rowg + tid;
#pragma unroll
            for (int j = 0; j < 10; ++j){
                const float sv = sScore[tid*10 + j];
                out[(size_t)NROWS    + rg*10 + j] = sv - m - l;
                out[(size_t)NROWS*11 + rg*10 + j] = sv;
            }
        }
    }
}

extern "C" void kernel_launch(void* const* d_in, const int* in_sizes, int n_in,
                              void* d_out, int out_size, void* d_ws, size_t ws_size,
                              hipStream_t stream) {
    (void)in_sizes; (void)n_in; (void)ws_size; (void)out_size;
    const float* cum  = (const float*)d_in[0];
    const float* inp  = (const float*)d_in[1];
    const float* pos  = (const float*)d_in[2];
    const float* ln1w = (const float*)d_in[3];
    const float* ln1b = (const float*)d_in[4];
    const float* ln2w = (const float*)d_in[5];
    const float* ln2b = (const float*)d_in[6];
    const float* ln3w = (const float*)d_in[7];
    const float* ln3b = (const float*)d_in[8];
    const float* n1g  = (const float*)d_in[9];
    const float* n1b  = (const float*)d_in[10];
    const float* n2g  = (const float*)d_in[11];
    const float* n2b  = (const float*)d_in[12];
    const float* n3g  = (const float*)d_in[13];
    const float* n3b  = (const float*)d_in[14];
    const float* p1w  = (const float*)d_in[15];
    const float* p1b  = (const float*)d_in[16];
    const float* p2w  = (const float*)d_in[17];
    const float* p2b  = (const float*)d_in[18];
    const float* p3w  = (const float*)d_in[19];
    const float* p3b  = (const float*)d_in[20];
    const float* pn1g = (const float*)d_in[21];
    const float* pn1b = (const float*)d_in[22];
    const float* pn2g = (const float*)d_in[23];
    const float* pn2b = (const float*)d_in[24];
    const float* pn3g = (const float*)d_in[25];
    const float* pn3b = (const float*)d_in[26];

    ushort_t* wbf = (ushort_t*)d_ws;
    float*    wf  = (float*)((char*)d_ws + BF16_BYTES);
    float*    out = (float*)d_out;

    hipLaunchKernelGGL(bcq_prep, dim3(387), dim3(256), 0, stream,
        ln1w, ln1b, ln2w, ln2b, ln3w, ln3b,
        n1g, n1b, n2g, n2b, n3g, n3b,
        p1w, p1b, p2w, p2b, p3w, p3b,
        pn1g, pn1b, pn2g, pn2b, pn3g, pn3b,
        wbf, wf);

    hipLaunchKernelGGL(bcq_main, dim3((NROWS/BM)*2), dim3(256), 0, stream,
        cum, inp, pos, wbf, wf, out);
}